// Round 4
// baseline (16553.633 us; speedup 1.0000x reference)
//
#include <hip/hip_runtime.h>

typedef _Float16 half8 __attribute__((ext_vector_type(8)));
typedef float f32x4 __attribute__((ext_vector_type(4)));

__device__ __forceinline__ float sigmoidf_(float x) { return 1.0f / (1.0f + __expf(-x)); }
__device__ __forceinline__ float tanhf_(float x) {
    // tanh(x) = 1 - 2/(1+e^{2x}); robust for large |x|
    return 1.0f - 2.0f / (1.0f + __expf(2.0f * x));
}

// Column of the gate matrix owned by (wave w, tile n, lane-col lc):
// gate q = n>>1, sub-tile s = n&1, h-index j = 32w + 16s + lc
__device__ __forceinline__ int col0_of(int w, int n) {
    return 256 * (n >> 1) + 32 * w + 16 * (n & 1);
}

// ---------------------------------------------------------------------------
// PREP: f16 B-fragment tables for U1,U2,W2 (K=256) and W1 (K=128).
// Layout: F[w][n][kk][lane] half8, b[j] = M[kk*32+(l>>4)*8+j][col0_of(w,n)+(l&15)]
// ---------------------------------------------------------------------------
__global__ void prep_kernel(const float* __restrict__ U1, const float* __restrict__ U2,
                            const float* __restrict__ W1, const float* __restrict__ W2,
                            half8* __restrict__ U1f, half8* __restrict__ U2f,
                            half8* __restrict__ W1f, half8* __restrict__ W2f) {
    int id = blockIdx.x * 512 + threadIdx.x;  // 0..32767
    int l = id & 63;
    {
        int kk = (id >> 6) & 7, n = (id >> 9) & 7, w = (id >> 12) & 7;
        int col = col0_of(w, n) + (l & 15);
        int k0 = kk * 32 + (l >> 4) * 8;
        half8 a, b, d;
#pragma unroll
        for (int j = 0; j < 8; ++j) {
            a[j] = (_Float16)U1[(k0 + j) * 1024 + col];
            b[j] = (_Float16)U2[(k0 + j) * 1024 + col];
            d[j] = (_Float16)W2[(k0 + j) * 1024 + col];
        }
        U1f[id] = a; U2f[id] = b; W2f[id] = d;
    }
    if (id < 16384) {  // W1: K=128 -> KK=4
        int kk = (id >> 6) & 3, n = (id >> 8) & 7, w = (id >> 11) & 7;
        int col = col0_of(w, n) + (l & 15);
        int k0 = kk * 32 + (l >> 4) * 8;
        half8 d;
#pragma unroll
        for (int j = 0; j < 8; ++j) d[j] = (_Float16)W1[(k0 + j) * 1024 + col];
        W1f[id] = d;
    }
}

// ---------------------------------------------------------------------------
// GEMM_XW (f16 MFMA, f32 accumulate): xw[tl][g][w][n][lane] f32x4 (C-frag layout)
// 4 timesteps per block (W fragments reused). A staged in LDS f16, st_16x32 swizzle.
// ---------------------------------------------------------------------------
template <int K>
__global__ __launch_bounds__(512)
void gemm_xw(const void* __restrict__ Ain, const half8* __restrict__ Wf,
             const float* __restrict__ bias, f32x4* __restrict__ xw, int t0) {
    constexpr int KBLK = K / 8, KK = K / 32;
    __shared__ _Float16 a_lds[4 * 16 * K];
    int bid = blockIdx.x, tlb = bid >> 3, g = bid & 7, tid = threadIdx.x;

    for (int idx = tid; idx < 4 * 16 * KBLK; idx += 512) {
        int tq = idx / (16 * KBLK), rem = idx % (16 * KBLK);
        int row = rem / KBLK, kb = rem % KBLK;
        half8 hv;
        if constexpr (K == 128) {
            const float* src = (const float*)Ain +
                ((size_t)(16 * g + row) * 1024 + (size_t)(t0 + tlb * 4 + tq)) * 128 + kb * 8;
            f32x4 p0 = *(const f32x4*)src, p1 = *(const f32x4*)(src + 4);
#pragma unroll
            for (int j = 0; j < 4; ++j) { hv[j] = (_Float16)p0[j]; hv[4 + j] = (_Float16)p1[j]; }
        } else {
            const _Float16* src = (const _Float16*)Ain +
                (((size_t)(tlb * 4 + tq) * 8 + g) * 16 + row) * 256 + kb * 8;
            hv = *(const half8*)src;
        }
        *(half8*)((char*)a_lds + (size_t)tq * 16 * K * 2 + row * K * 2 +
                  ((kb ^ (row & 7)) << 4)) = hv;
    }
    __syncthreads();

    int w = tid >> 6, l = tid & 63, lrow = l & 15, lk = l >> 4;
    float bs[8];
#pragma unroll
    for (int n = 0; n < 8; ++n) bs[n] = bias[col0_of(w, n) + lrow];
    f32x4 acc[4][8];
#pragma unroll
    for (int tq = 0; tq < 4; ++tq)
#pragma unroll
        for (int n = 0; n < 8; ++n) acc[tq][n] = f32x4{bs[n], bs[n], bs[n], bs[n]};

#pragma unroll
    for (int kk = 0; kk < KK; ++kk) {
        half8 bf[8];
#pragma unroll
        for (int n = 0; n < 8; ++n) bf[n] = Wf[((w * 8 + n) * KK + kk) * 64 + l];
#pragma unroll
        for (int tq = 0; tq < 4; ++tq) {
            half8 af = *(const half8*)((char*)a_lds + (size_t)tq * 16 * K * 2 + lrow * K * 2 +
                                       (((kk * 4 + lk) ^ (lrow & 7)) << 4));
#pragma unroll
            for (int n = 0; n < 8; ++n)
                acc[tq][n] = __builtin_amdgcn_mfma_f32_16x16x32_f16(af, bf[n], acc[tq][n], 0, 0, 0);
        }
    }
#pragma unroll
    for (int tq = 0; tq < 4; ++tq) {
        size_t base = (((size_t)(tlb * 4 + tq) * 8 + g) * 8 + w) * 512;
#pragma unroll
        for (int n = 0; n < 8; ++n) xw[base + n * 64 + l] = acc[tq][n];
    }
}

// ---------------------------------------------------------------------------
// REC: persistent LSTM recurrence. 8 blocks x 512 threads (8 waves, 1/CU).
// U f16 per wave: tiles 2,4,3,5 pinned in AGPRs (128), tiles 6,7 in LDS,
// tiles 0,1 streamed from L2 via full-tile staging regs (reload-after-use,
// one-step in-flight window). h f16 double-buffered LDS (st_16x32 swizzle);
// c in registers. One raw s_barrier per step (lgkmcnt drain only).
// ---------------------------------------------------------------------------
__global__ __launch_bounds__(512) __attribute__((amdgpu_waves_per_eu(2, 2)))
void rec_kernel(const f32x4* __restrict__ xw,    // [TC][8][8][8][64] f32x4
                const half8* __restrict__ Uf,    // [8][8][8][64] half8
                _Float16* __restrict__ h1out,    // [TC][8][16][256] f16 (if writeH)
                _Float16* __restrict__ state_h,  // [8][4096] raw swizzled image
                float* __restrict__ state_c,     // [8][512][8]
                int TC, int first, int writeH) {
    __shared__ half8 u_lds[8192];        // 128 KB: [w][slot(2)][kk(8)][l(64)]
    __shared__ _Float16 h_lds[2][4096];  // 2 x 8 KB, st_16x32-swizzled [16][256]

    int g = blockIdx.x, tid = threadIdx.x, w = tid >> 6, l = tid & 63;
    int lrow = l & 15, lk = l >> 4;

    const half8* ufw = Uf + (size_t)w * 4096;  // [n][kk][l]

    // tiles 2,4,3,5 -> AGPR file (arch-VGPR cap of 128 doesn't apply there)
    half8 ua[4][8];
#pragma unroll
    for (int kk = 0; kk < 8; ++kk) {
        ua[0][kk] = ufw[(2 * 8 + kk) * 64 + l];
        ua[1][kk] = ufw[(4 * 8 + kk) * 64 + l];
        ua[2][kk] = ufw[(3 * 8 + kk) * 64 + l];
        ua[3][kk] = ufw[(5 * 8 + kk) * 64 + l];
    }
#pragma unroll
    for (int n = 0; n < 4; ++n)
#pragma unroll
        for (int kk = 0; kk < 8; ++kk) asm volatile("" : "+a"(ua[n][kk]));

    for (int slot = 0; slot < 2; ++slot)  // tiles 6,7 -> LDS
        for (int kk = 0; kk < 8; ++kk)
            u_lds[(w * 2 + slot) * 512 + kk * 64 + l] = ufw[((6 + slot) * 8 + kk) * 64 + l];

    // tiles 0,1 -> streaming staging regs (initial fill)
    half8 s0[8], s1[8];
#pragma unroll
    for (int kk = 0; kk < 8; ++kk) {
        s0[kk] = ufw[(0 * 8 + kk) * 64 + l];
        s1[kk] = ufw[(1 * 8 + kk) * 64 + l];
    }

    float c[8];
    if (first) {
        for (int i = tid; i < 4096; i += 512) h_lds[0][i] = (_Float16)0.0f;
#pragma unroll
        for (int i = 0; i < 8; ++i) c[i] = 0.0f;
    } else {
        for (int i = tid; i < 4096; i += 512) h_lds[0][i] = state_h[(size_t)g * 4096 + i];
        const f32x4* cs = (const f32x4*)(state_c + ((size_t)g * 512 + tid) * 8);
        f32x4 c0 = cs[0], c1 = cs[1];
#pragma unroll
        for (int i = 0; i < 4; ++i) { c[i] = c0[i]; c[4 + i] = c1[i]; }
    }

    f32x4 acc[8];
    {
        const f32x4* xw0 = xw + ((size_t)g * 8 + w) * 512;
#pragma unroll
        for (int n = 0; n < 8; ++n) acc[n] = xw0[n * 64 + l];
    }
    __syncthreads();

#define ACT(s, r)                                                                     \
    {                                                                                 \
        float ii = sigmoidf_(acc[0 + (s)][r]);                                        \
        float ff = sigmoidf_(acc[2 + (s)][r]);                                        \
        float gg = tanhf_(acc[4 + (s)][r]);                                           \
        float oo = sigmoidf_(acc[6 + (s)][r]);                                        \
        float cn = ff * c[(s) * 4 + (r)] + ii * gg;                                   \
        c[(s) * 4 + (r)] = cn;                                                        \
        float hf = oo * tanhf_(cn);                                                   \
        int j = 32 * w + 16 * (s) + lrow;                                             \
        int row = lk * 4 + (r);                                                       \
        int bk = (j >> 3) ^ (row & 7);                                                \
        *(_Float16*)(hn + row * 512 + (bk << 4) + (j & 7) * 2) = (_Float16)hf;        \
        if (writeH) h1out[(((size_t)t * 8 + g) * 16 + row) * 256 + j] = (_Float16)hf; \
    }

    for (int t = 0; t < TC; ++t) {
        const char* hb = (const char*)h_lds[t & 1];
        char* hn = (char*)h_lds[(t + 1) & 1];
        // opaque pointer: stops LICM from proving the stream reloads redundant
        const half8* pS = ufw;
        asm volatile("" : "+v"(pS));

        // PASS 1: even tiles {0,2,4,6} (sub-tile s=0 of gates i,f,g,o)
#pragma unroll
        for (int kk = 0; kk < 8; ++kk) {
            half8 af = *(const half8*)(hb + lrow * 512 +
                                       (((kk * 4 + lk) ^ (lrow & 7)) << 4));
            acc[2] = __builtin_amdgcn_mfma_f32_16x16x32_f16(af, ua[0][kk], acc[2], 0, 0, 0);
            acc[4] = __builtin_amdgcn_mfma_f32_16x16x32_f16(af, ua[1][kk], acc[4], 0, 0, 0);
            acc[6] = __builtin_amdgcn_mfma_f32_16x16x32_f16(
                af, u_lds[(w * 2 + 0) * 512 + kk * 64 + l], acc[6], 0, 0, 0);
            acc[0] = __builtin_amdgcn_mfma_f32_16x16x32_f16(af, s0[kk], acc[0], 0, 0, 0);
            s0[kk] = pS[(0 * 8 + kk) * 64 + l];  // reload for t+1 (same data, L2-hot)
        }
        // PASS 2: odd tiles {1,3,5,7}; activation of s=0 interleaved
#pragma unroll
        for (int kk = 0; kk < 8; ++kk) {
            half8 af = *(const half8*)(hb + lrow * 512 +
                                       (((kk * 4 + lk) ^ (lrow & 7)) << 4));
            acc[3] = __builtin_amdgcn_mfma_f32_16x16x32_f16(af, ua[2][kk], acc[3], 0, 0, 0);
            acc[5] = __builtin_amdgcn_mfma_f32_16x16x32_f16(af, ua[3][kk], acc[5], 0, 0, 0);
            acc[7] = __builtin_amdgcn_mfma_f32_16x16x32_f16(
                af, u_lds[(w * 2 + 1) * 512 + kk * 64 + l], acc[7], 0, 0, 0);
            acc[1] = __builtin_amdgcn_mfma_f32_16x16x32_f16(af, s1[kk], acc[1], 0, 0, 0);
            s1[kk] = pS[(1 * 8 + kk) * 64 + l];  // reload for t+1
            if (kk == 4) ACT(0, 0);
            if (kk == 5) ACT(0, 1);
            if (kk == 6) ACT(0, 2);
            if (kk == 7) ACT(0, 3);
        }
        // prefetch xw[t+1] for even tiles (acc evens consumed by ACT(0,*))
        int tn = (t + 1 < TC) ? t + 1 : t;
        const f32x4* xwn = xw + (((size_t)tn * 8 + g) * 8 + w) * 512;
        acc[0] = xwn[0 * 64 + l]; acc[2] = xwn[2 * 64 + l];
        acc[4] = xwn[4 * 64 + l]; acc[6] = xwn[6 * 64 + l];
        ACT(1, 0); ACT(1, 1); ACT(1, 2); ACT(1, 3);
        acc[1] = xwn[1 * 64 + l]; acc[3] = xwn[3 * 64 + l];
        acc[5] = xwn[5 * 64 + l]; acc[7] = xwn[7 * 64 + l];
        // barrier: drain LDS ops only; global loads/stores stay in flight
        asm volatile("s_waitcnt lgkmcnt(0)" ::: "memory");
        __builtin_amdgcn_s_barrier();
        __builtin_amdgcn_sched_barrier(0);
    }
#undef ACT

    // save state (TC even -> final h image in buffer 0)
    for (int i = tid; i < 4096; i += 512) state_h[(size_t)g * 4096 + i] = h_lds[0][i];
    f32x4 c0, c1;
#pragma unroll
    for (int i = 0; i < 4; ++i) { c0[i] = c[i]; c1[i] = c[4 + i]; }
    f32x4* cs = (f32x4*)(state_c + ((size_t)g * 512 + tid) * 8);
    cs[0] = c0; cs[1] = c1;
}

// ---------------------------------------------------------------------------
// DENSE head: out[b] = relu(relu(h2 @ Wd1 + bd1) @ Wd2 + bd2); h2 is f16
// ---------------------------------------------------------------------------
__global__ void dense_kernel(const _Float16* __restrict__ h2, const float* __restrict__ Wd1,
                             const float* __restrict__ bd1, const float* __restrict__ Wd2,
                             const float* __restrict__ bd2, float* __restrict__ out) {
    __shared__ float hrow[256];
    __shared__ float red[128];
    int rg = blockIdx.x;  // batch row 0..127; g = rg>>4, row = rg&15
    int g = rg >> 4, row = rg & 15;
    int tid = threadIdx.x;  // 128
    hrow[tid] = (float)h2[((size_t)g * 16 + row) * 256 + tid];
    hrow[tid + 128] = (float)h2[((size_t)g * 16 + row) * 256 + tid + 128];
    __syncthreads();
    float a = 0.0f;
    for (int k = 0; k < 256; ++k) a += hrow[k] * Wd1[k * 128 + tid];
    a = fmaxf(a + bd1[tid], 0.0f);
    red[tid] = a * Wd2[tid];
    __syncthreads();
    for (int s = 64; s > 0; s >>= 1) {
        if (tid < s) red[tid] += red[tid + s];
        __syncthreads();
    }
    if (tid == 0) out[rg] = fmaxf(red[0] + bd2[0], 0.0f);
}

// ---------------------------------------------------------------------------
extern "C" void kernel_launch(void* const* d_in, const int* in_sizes, int n_in,
                              void* d_out, int out_size, void* d_ws, size_t ws_size,
                              hipStream_t stream) {
    const float* x   = (const float*)d_in[0];
    const float* W1  = (const float*)d_in[1];
    const float* U1  = (const float*)d_in[2];
    const float* b1  = (const float*)d_in[3];
    const float* W2  = (const float*)d_in[4];
    const float* U2  = (const float*)d_in[5];
    const float* b2  = (const float*)d_in[6];
    const float* Wd1 = (const float*)d_in[7];
    const float* bd1 = (const float*)d_in[8];
    const float* Wd2 = (const float*)d_in[9];
    const float* bd2 = (const float*)d_in[10];
    float* out = (float*)d_out;

    char* ws = (char*)d_ws;
    size_t off = 0;
    auto alloc = [&](size_t bytes) -> char* {
        char* p = ws + off;
        off = (off + bytes + 1023) & ~(size_t)1023;
        return p;
    };
    half8* U1f    = (half8*)alloc(32768 * 16);
    half8* U2f    = (half8*)alloc(32768 * 16);
    half8* W1f    = (half8*)alloc(16384 * 16);
    half8* W2f    = (half8*)alloc(32768 * 16);
    _Float16* s1h = (_Float16*)alloc(8 * 4096 * 2);
    float* s1c    = (float*)alloc(8 * 512 * 8 * 4);
    _Float16* s2h = (_Float16*)alloc(8 * 4096 * 2);
    float* s2c    = (float*)alloc(8 * 512 * 8 * 4);
    size_t fixed = off;

    int TC = 256;
    while (TC > 4 && fixed + (size_t)TC * (512 + 64) * 1024 + 65536 > ws_size) TC >>= 1;
    f32x4* xwb    = (f32x4*)alloc((size_t)TC * 32768 * 16);
    _Float16* h1c = (_Float16*)alloc((size_t)TC * 32768 * 2);
    int chunks = 1024 / TC;

    prep_kernel<<<dim3(64), dim3(512), 0, stream>>>(U1, U2, W1, W2, U1f, U2f, W1f, W2f);

    for (int c = 0; c < chunks; ++c) {
        gemm_xw<128><<<dim3((TC / 4) * 8), dim3(512), 0, stream>>>(x, W1f, b1, xwb, c * TC);
        rec_kernel<<<dim3(8), dim3(512), 0, stream>>>(xwb, U1f, h1c, s1h, s1c, TC,
                                                      (c == 0) ? 1 : 0, 1);
        gemm_xw<256><<<dim3((TC / 4) * 8), dim3(512), 0, stream>>>(h1c, W2f, b2, xwb, 0);
        rec_kernel<<<dim3(8), dim3(512), 0, stream>>>(xwb, U2f, h1c, s2h, s2c, TC,
                                                      (c == 0) ? 1 : 0, (c == chunks - 1) ? 1 : 0);
    }

    dense_kernel<<<dim3(128), dim3(128), 0, stream>>>(h1c + (size_t)(TC - 1) * 32768, Wd1, bd1,
                                                      Wd2, bd2, out);
}

// Round 5
// 14360.405 us; speedup vs baseline: 1.1527x; 1.1527x over previous
//
#include <hip/hip_runtime.h>

typedef _Float16 half8 __attribute__((ext_vector_type(8)));
typedef float f32x4 __attribute__((ext_vector_type(4)));

__device__ __forceinline__ float sigmoidf_(float x) { return 1.0f / (1.0f + __expf(-x)); }
__device__ __forceinline__ float tanhf_(float x) {
    // tanh(x) = 1 - 2/(1+e^{2x}); robust for large |x|
    return 1.0f - 2.0f / (1.0f + __expf(2.0f * x));
}

// MFMA with B operand read natively from AGPR (gfx950 allows A/B in AGPR).
// Avoids the v_accvgpr_read storm the builtin generates for "+a" values.
#define MFMA_AG(accv, afv, bfa)                                        \
    asm("v_mfma_f32_16x16x32_f16 %0, %1, %2, %0"                        \
        : "+v"(accv)                                                    \
        : "v"(afv), "a"(bfa))

// Column of the gate matrix owned by (wave w, tile n, lane-col lc):
// gate q = n>>1, sub-tile s = n&1, h-index j = 32w + 16s + lc
__device__ __forceinline__ int col0_of(int w, int n) {
    return 256 * (n >> 1) + 32 * w + 16 * (n & 1);
}

// ---------------------------------------------------------------------------
// PREP: f16 B-fragment tables for U1,U2,W2 (K=256) and W1 (K=128).
// Layout: F[w][n][kk][lane] half8, b[j] = M[kk*32+(l>>4)*8+j][col0_of(w,n)+(l&15)]
// ---------------------------------------------------------------------------
__global__ void prep_kernel(const float* __restrict__ U1, const float* __restrict__ U2,
                            const float* __restrict__ W1, const float* __restrict__ W2,
                            half8* __restrict__ U1f, half8* __restrict__ U2f,
                            half8* __restrict__ W1f, half8* __restrict__ W2f) {
    int id = blockIdx.x * 512 + threadIdx.x;  // 0..32767
    int l = id & 63;
    {
        int kk = (id >> 6) & 7, n = (id >> 9) & 7, w = (id >> 12) & 7;
        int col = col0_of(w, n) + (l & 15);
        int k0 = kk * 32 + (l >> 4) * 8;
        half8 a, b, d;
#pragma unroll
        for (int j = 0; j < 8; ++j) {
            a[j] = (_Float16)U1[(k0 + j) * 1024 + col];
            b[j] = (_Float16)U2[(k0 + j) * 1024 + col];
            d[j] = (_Float16)W2[(k0 + j) * 1024 + col];
        }
        U1f[id] = a; U2f[id] = b; W2f[id] = d;
    }
    if (id < 16384) {  // W1: K=128 -> KK=4
        int kk = (id >> 6) & 3, n = (id >> 8) & 7, w = (id >> 11) & 7;
        int col = col0_of(w, n) + (l & 15);
        int k0 = kk * 32 + (l >> 4) * 8;
        half8 d;
#pragma unroll
        for (int j = 0; j < 8; ++j) d[j] = (_Float16)W1[(k0 + j) * 1024 + col];
        W1f[id] = d;
    }
}

// ---------------------------------------------------------------------------
// GEMM_XW (f16 MFMA, f32 accumulate): xw[tl][g][w][n][lane] f32x4 (C-frag layout)
// 4 timesteps per block (W fragments reused). A staged in LDS f16, st_16x32 swizzle.
// ---------------------------------------------------------------------------
template <int K>
__global__ __launch_bounds__(512)
void gemm_xw(const void* __restrict__ Ain, const half8* __restrict__ Wf,
             const float* __restrict__ bias, f32x4* __restrict__ xw, int t0) {
    constexpr int KBLK = K / 8, KK = K / 32;
    __shared__ _Float16 a_lds[4 * 16 * K];
    int bid = blockIdx.x, tlb = bid >> 3, g = bid & 7, tid = threadIdx.x;

    for (int idx = tid; idx < 4 * 16 * KBLK; idx += 512) {
        int tq = idx / (16 * KBLK), rem = idx % (16 * KBLK);
        int row = rem / KBLK, kb = rem % KBLK;
        half8 hv;
        if constexpr (K == 128) {
            const float* src = (const float*)Ain +
                ((size_t)(16 * g + row) * 1024 + (size_t)(t0 + tlb * 4 + tq)) * 128 + kb * 8;
            f32x4 p0 = *(const f32x4*)src, p1 = *(const f32x4*)(src + 4);
#pragma unroll
            for (int j = 0; j < 4; ++j) { hv[j] = (_Float16)p0[j]; hv[4 + j] = (_Float16)p1[j]; }
        } else {
            const _Float16* src = (const _Float16*)Ain +
                (((size_t)(tlb * 4 + tq) * 8 + g) * 16 + row) * 256 + kb * 8;
            hv = *(const half8*)src;
        }
        *(half8*)((char*)a_lds + (size_t)tq * 16 * K * 2 + row * K * 2 +
                  ((kb ^ (row & 7)) << 4)) = hv;
    }
    __syncthreads();

    int w = tid >> 6, l = tid & 63, lrow = l & 15, lk = l >> 4;
    float bs[8];
#pragma unroll
    for (int n = 0; n < 8; ++n) bs[n] = bias[col0_of(w, n) + lrow];
    f32x4 acc[4][8];
#pragma unroll
    for (int tq = 0; tq < 4; ++tq)
#pragma unroll
        for (int n = 0; n < 8; ++n) acc[tq][n] = f32x4{bs[n], bs[n], bs[n], bs[n]};

#pragma unroll
    for (int kk = 0; kk < KK; ++kk) {
        half8 bf[8];
#pragma unroll
        for (int n = 0; n < 8; ++n) bf[n] = Wf[((w * 8 + n) * KK + kk) * 64 + l];
#pragma unroll
        for (int tq = 0; tq < 4; ++tq) {
            half8 af = *(const half8*)((char*)a_lds + (size_t)tq * 16 * K * 2 + lrow * K * 2 +
                                       (((kk * 4 + lk) ^ (lrow & 7)) << 4));
#pragma unroll
            for (int n = 0; n < 8; ++n)
                acc[tq][n] = __builtin_amdgcn_mfma_f32_16x16x32_f16(af, bf[n], acc[tq][n], 0, 0, 0);
        }
    }
#pragma unroll
    for (int tq = 0; tq < 4; ++tq) {
        size_t base = (((size_t)(tlb * 4 + tq) * 8 + g) * 8 + w) * 512;
#pragma unroll
        for (int n = 0; n < 8; ++n) xw[base + n * 64 + l] = acc[tq][n];
    }
}

// ---------------------------------------------------------------------------
// REC: persistent LSTM recurrence. 8 blocks x 512 threads (8 waves, 1 block/CU,
// 2 waves/SIMD -> 256 unified regs/wave = 128 arch + 128 AGPR).
// U f16 per wave (8 tiles): {0,2,1,3} in AGPR (128, consumed via asm MFMA),
// {4,5} in LDS, {6,7} streamed from L2 through ONE shared 32-reg rolling
// buffer (use slot kk, reload it with the other tile; ~550cy reuse window).
// h f16 double-buffered LDS (st_16x32 swizzle); c in registers.
// One raw s_barrier per step (lgkmcnt drain only).
// ---------------------------------------------------------------------------
__global__ __launch_bounds__(512) __attribute__((amdgpu_waves_per_eu(2, 2)))
void rec_kernel(const f32x4* __restrict__ xw,    // [TC][8][8][8][64] f32x4
                const half8* __restrict__ Uf,    // [8][8][8][64] half8
                _Float16* __restrict__ h1out,    // [TC][8][16][256] f16 (if writeH)
                _Float16* __restrict__ state_h,  // [8][4096] raw swizzled image
                float* __restrict__ state_c,     // [8][512][8]
                int TC, int first, int writeH) {
    __shared__ half8 u_lds[8192];        // 128 KB: [w][slot(2)][kk(8)][l(64)]
    __shared__ _Float16 h_lds[2][4096];  // 2 x 8 KB, st_16x32-swizzled [16][256]

    int g = blockIdx.x, tid = threadIdx.x, w = tid >> 6, l = tid & 63;
    int lrow = l & 15, lk = l >> 4;

    const half8* ufw = Uf + (size_t)w * 4096;  // [n][kk][l]

    // tiles 0,2,1,3 -> AGPR half of the unified file
    half8 ua[4][8];
#pragma unroll
    for (int kk = 0; kk < 8; ++kk) {
        ua[0][kk] = ufw[(0 * 8 + kk) * 64 + l];
        ua[1][kk] = ufw[(2 * 8 + kk) * 64 + l];
        ua[2][kk] = ufw[(1 * 8 + kk) * 64 + l];
        ua[3][kk] = ufw[(3 * 8 + kk) * 64 + l];
    }
#pragma unroll
    for (int n = 0; n < 4; ++n)
#pragma unroll
        for (int kk = 0; kk < 8; ++kk) asm volatile("" : "+a"(ua[n][kk]));

    for (int slot = 0; slot < 2; ++slot)  // tiles 4,5 -> LDS
        for (int kk = 0; kk < 8; ++kk)
            u_lds[(w * 2 + slot) * 512 + kk * 64 + l] = ufw[((4 + slot) * 8 + kk) * 64 + l];

    // shared stream buffer: starts as tile 6 (pass-1 consumer)
    half8 sbuf[8];
#pragma unroll
    for (int kk = 0; kk < 8; ++kk) sbuf[kk] = ufw[(6 * 8 + kk) * 64 + l];

    float c[8];
    if (first) {
        for (int i = tid; i < 4096; i += 512) h_lds[0][i] = (_Float16)0.0f;
#pragma unroll
        for (int i = 0; i < 8; ++i) c[i] = 0.0f;
    } else {
        for (int i = tid; i < 4096; i += 512) h_lds[0][i] = state_h[(size_t)g * 4096 + i];
        const f32x4* cs = (const f32x4*)(state_c + ((size_t)g * 512 + tid) * 8);
        f32x4 c0 = cs[0], c1 = cs[1];
#pragma unroll
        for (int i = 0; i < 4; ++i) { c[i] = c0[i]; c[4 + i] = c1[i]; }
    }

    f32x4 acc[8];
    {
        const f32x4* xw0 = xw + ((size_t)g * 8 + w) * 512;
#pragma unroll
        for (int n = 0; n < 8; ++n) acc[n] = xw0[n * 64 + l];
    }
    __syncthreads();

#define ACT(s, r)                                                                     \
    {                                                                                 \
        float ii = sigmoidf_(acc[0 + (s)][r]);                                        \
        float ff = sigmoidf_(acc[2 + (s)][r]);                                        \
        float gg = tanhf_(acc[4 + (s)][r]);                                           \
        float oo = sigmoidf_(acc[6 + (s)][r]);                                        \
        float cn = ff * c[(s) * 4 + (r)] + ii * gg;                                   \
        c[(s) * 4 + (r)] = cn;                                                        \
        float hf = oo * tanhf_(cn);                                                   \
        int j = 32 * w + 16 * (s) + lrow;                                             \
        int row = lk * 4 + (r);                                                       \
        int bk = (j >> 3) ^ (row & 7);                                                \
        *(_Float16*)(hn + row * 512 + (bk << 4) + (j & 7) * 2) = (_Float16)hf;        \
        if (writeH) h1out[(((size_t)t * 8 + g) * 16 + row) * 256 + j] = (_Float16)hf; \
    }

    for (int t = 0; t < TC; ++t) {
        const char* hb = (const char*)h_lds[t & 1];
        char* hn = (char*)h_lds[(t + 1) & 1];
        // opaque pointer: stops LICM/CSE from proving the stream reloads
        // redundant (which would keep both tiles resident = +64 arch regs)
        const half8* pS = ufw;
        asm volatile("" : "+v"(pS));

        // PASS 1: even tiles {0,2,4,6} (sub-tile s=0 of gates i,f,g,o)
#pragma unroll
        for (int kk = 0; kk < 8; ++kk) {
            half8 af = *(const half8*)(hb + lrow * 512 +
                                       (((kk * 4 + lk) ^ (lrow & 7)) << 4));
            MFMA_AG(acc[0], af, ua[0][kk]);
            MFMA_AG(acc[2], af, ua[1][kk]);
            acc[4] = __builtin_amdgcn_mfma_f32_16x16x32_f16(
                af, u_lds[(w * 2 + 0) * 512 + kk * 64 + l], acc[4], 0, 0, 0);
            acc[6] = __builtin_amdgcn_mfma_f32_16x16x32_f16(af, sbuf[kk], acc[6], 0, 0, 0);
            sbuf[kk] = pS[(7 * 8 + kk) * 64 + l];  // refill slot with tile 7
        }
        // PASS 2: odd tiles {1,3,5,7}; activation of s=0 interleaved
#pragma unroll
        for (int kk = 0; kk < 8; ++kk) {
            half8 af = *(const half8*)(hb + lrow * 512 +
                                       (((kk * 4 + lk) ^ (lrow & 7)) << 4));
            MFMA_AG(acc[1], af, ua[2][kk]);
            MFMA_AG(acc[3], af, ua[3][kk]);
            acc[5] = __builtin_amdgcn_mfma_f32_16x16x32_f16(
                af, u_lds[(w * 2 + 1) * 512 + kk * 64 + l], acc[5], 0, 0, 0);
            acc[7] = __builtin_amdgcn_mfma_f32_16x16x32_f16(af, sbuf[kk], acc[7], 0, 0, 0);
            sbuf[kk] = pS[(6 * 8 + kk) * 64 + l];  // refill slot with tile 6 (t+1)
            if (kk == 4) ACT(0, 0);
            if (kk == 5) ACT(0, 1);
            if (kk == 6) ACT(0, 2);
            if (kk == 7) ACT(0, 3);
        }
        // prefetch xw[t+1] for even tiles (acc evens consumed by ACT(0,*))
        int tn = (t + 1 < TC) ? t + 1 : t;
        const f32x4* xwn = xw + (((size_t)tn * 8 + g) * 8 + w) * 512;
        acc[0] = xwn[0 * 64 + l]; acc[2] = xwn[2 * 64 + l];
        acc[4] = xwn[4 * 64 + l]; acc[6] = xwn[6 * 64 + l];
        ACT(1, 0); ACT(1, 1); ACT(1, 2); ACT(1, 3);
        acc[1] = xwn[1 * 64 + l]; acc[3] = xwn[3 * 64 + l];
        acc[5] = xwn[5 * 64 + l]; acc[7] = xwn[7 * 64 + l];
        // barrier: drain LDS ops only; global loads/stores stay in flight
        asm volatile("s_waitcnt lgkmcnt(0)" ::: "memory");
        __builtin_amdgcn_s_barrier();
        __builtin_amdgcn_sched_barrier(0);
    }
#undef ACT

    // save state (TC even -> final h image in buffer 0)
    for (int i = tid; i < 4096; i += 512) state_h[(size_t)g * 4096 + i] = h_lds[0][i];
    f32x4 c0, c1;
#pragma unroll
    for (int i = 0; i < 4; ++i) { c0[i] = c[i]; c1[i] = c[4 + i]; }
    f32x4* cs = (f32x4*)(state_c + ((size_t)g * 512 + tid) * 8);
    cs[0] = c0; cs[1] = c1;
}

// ---------------------------------------------------------------------------
// DENSE head: out[b] = relu(relu(h2 @ Wd1 + bd1) @ Wd2 + bd2); h2 is f16
// ---------------------------------------------------------------------------
__global__ void dense_kernel(const _Float16* __restrict__ h2, const float* __restrict__ Wd1,
                             const float* __restrict__ bd1, const float* __restrict__ Wd2,
                             const float* __restrict__ bd2, float* __restrict__ out) {
    __shared__ float hrow[256];
    __shared__ float red[128];
    int rg = blockIdx.x;  // batch row 0..127; g = rg>>4, row = rg&15
    int g = rg >> 4, row = rg & 15;
    int tid = threadIdx.x;  // 128
    hrow[tid] = (float)h2[((size_t)g * 16 + row) * 256 + tid];
    hrow[tid + 128] = (float)h2[((size_t)g * 16 + row) * 256 + tid + 128];
    __syncthreads();
    float a = 0.0f;
    for (int k = 0; k < 256; ++k) a += hrow[k] * Wd1[k * 128 + tid];
    a = fmaxf(a + bd1[tid], 0.0f);
    red[tid] = a * Wd2[tid];
    __syncthreads();
    for (int s = 64; s > 0; s >>= 1) {
        if (tid < s) red[tid] += red[tid + s];
        __syncthreads();
    }
    if (tid == 0) out[rg] = fmaxf(red[0] + bd2[0], 0.0f);
}

// ---------------------------------------------------------------------------
extern "C" void kernel_launch(void* const* d_in, const int* in_sizes, int n_in,
                              void* d_out, int out_size, void* d_ws, size_t ws_size,
                              hipStream_t stream) {
    const float* x   = (const float*)d_in[0];
    const float* W1  = (const float*)d_in[1];
    const float* U1  = (const float*)d_in[2];
    const float* b1  = (const float*)d_in[3];
    const float* W2  = (const float*)d_in[4];
    const float* U2  = (const float*)d_in[5];
    const float* b2  = (const float*)d_in[6];
    const float* Wd1 = (const float*)d_in[7];
    const float* bd1 = (const float*)d_in[8];
    const float* Wd2 = (const float*)d_in[9];
    const float* bd2 = (const float*)d_in[10];
    float* out = (float*)d_out;

    char* ws = (char*)d_ws;
    size_t off = 0;
    auto alloc = [&](size_t bytes) -> char* {
        char* p = ws + off;
        off = (off + bytes + 1023) & ~(size_t)1023;
        return p;
    };
    half8* U1f    = (half8*)alloc(32768 * 16);
    half8* U2f    = (half8*)alloc(32768 * 16);
    half8* W1f    = (half8*)alloc(16384 * 16);
    half8* W2f    = (half8*)alloc(32768 * 16);
    _Float16* s1h = (_Float16*)alloc(8 * 4096 * 2);
    float* s1c    = (float*)alloc(8 * 512 * 8 * 4);
    _Float16* s2h = (_Float16*)alloc(8 * 4096 * 2);
    float* s2c    = (float*)alloc(8 * 512 * 8 * 4);
    size_t fixed = off;

    int TC = 256;
    while (TC > 4 && fixed + (size_t)TC * (512 + 64) * 1024 + 65536 > ws_size) TC >>= 1;
    f32x4* xwb    = (f32x4*)alloc((size_t)TC * 32768 * 16);
    _Float16* h1c = (_Float16*)alloc((size_t)TC * 32768 * 2);
    int chunks = 1024 / TC;

    prep_kernel<<<dim3(64), dim3(512), 0, stream>>>(U1, U2, W1, W2, U1f, U2f, W1f, W2f);

    for (int c = 0; c < chunks; ++c) {
        gemm_xw<128><<<dim3((TC / 4) * 8), dim3(512), 0, stream>>>(x, W1f, b1, xwb, c * TC);
        rec_kernel<<<dim3(8), dim3(512), 0, stream>>>(xwb, U1f, h1c, s1h, s1c, TC,
                                                      (c == 0) ? 1 : 0, 1);
        gemm_xw<256><<<dim3((TC / 4) * 8), dim3(512), 0, stream>>>(h1c, W2f, b2, xwb, 0);
        rec_kernel<<<dim3(8), dim3(512), 0, stream>>>(xwb, U2f, h1c, s2h, s2c, TC,
                                                      (c == 0) ? 1 : 0, (c == chunks - 1) ? 1 : 0);
    }

    dense_kernel<<<dim3(128), dim3(128), 0, stream>>>(h1c + (size_t)(TC - 1) * 32768, Wd1, bd1,
                                                      Wd2, bd2, out);
}